// Round 5
// baseline (661.184 us; speedup 1.0000x reference)
//
#include <hip/hip_runtime.h>
#include <math.h>

#define N_NODES 100000
#define FIN     512
#define H1H     8
#define C1C     8
#define HC1     64
#define NCLS    40
#define NEG_SLOPE 0.2f

// CSR bucketing: 256 dst-nodes per bucket (R2 config, best known)
#define NPB   256
#define NBUK  391          // ceil(100000/256)
#define EPB   4096         // edges per block in bucket count/fill

// ---------------- Layer-1 GEMM + fused attention dots (R4 rewrite) ----------------
// Wave-uniform W columns (SGPR s_load operand), lane-per-row x from LDS.
// Per k: 1 ds_read_b32 + 16 FMA  (was 3 ds_read_b128 per 32 FMA -> LDS-bound).
#define TM 64
#define BK 16
#define XPAD 68

__global__ __launch_bounds__(256) void k_gemm1(const float* __restrict__ x,
                                               const float* __restrict__ W1,
                                               const float* __restrict__ att_src,
                                               const float* __restrict__ att_dst,
                                               float* __restrict__ h1,
                                               float* __restrict__ a_src,
                                               float* __restrict__ a_dst) {
    __shared__ float xs[2][BK][XPAD];
    const int tx   = threadIdx.x;
    const int lane = tx & 63;
    const int wid  = __builtin_amdgcn_readfirstlane(tx >> 6);
    const int c0   = wid << 4;              // 16 cols per wave (heads 2w, 2w+1)
    const int row_base = blockIdx.x * TM;
    const int gr   = row_base + lane;       // this lane's output row
    const bool valid = gr < N_NODES;

    // staging: 64 rows x 16 k = 256 float4, one per thread
    const int sr  = tx >> 2;                // 0..63 row
    const int sk  = (tx & 3) << 2;          // 0,4,8,12
    const int sgr = row_base + sr;
    const bool svalid = sgr < N_NODES;

    float4 xr4;
    auto load_regs = [&](int k0) {
        xr4 = svalid ? *(const float4*)(x + (size_t)sgr * FIN + k0 + sk)
                     : make_float4(0.f, 0.f, 0.f, 0.f);
    };
    auto store_lds = [&](int buf) {
        xs[buf][sk + 0][sr] = xr4.x;
        xs[buf][sk + 1][sr] = xr4.y;
        xs[buf][sk + 2][sr] = xr4.z;
        xs[buf][sk + 3][sr] = xr4.w;
    };

    float acc[16];
#pragma unroll
    for (int j = 0; j < 16; j++) acc[j] = 0.f;

    load_regs(0);
    store_lds(0);
    __syncthreads();

    int buf = 0;
    for (int k0 = 0; k0 < FIN; k0 += BK, buf ^= 1) {
        const bool more = (k0 + BK < FIN);
        if (more) load_regs(k0 + BK);
#pragma unroll
        for (int k = 0; k < BK; k++) {
            const float xv = xs[buf][k][lane];
            const float* wr = W1 + (size_t)(k0 + k) * HC1 + c0;  // wave-uniform -> s_load
#pragma unroll
            for (int j = 0; j < 16; j++)
                acc[j] = fmaf(xv, wr[j], acc[j]);
        }
        if (more) {
            store_lds(buf ^ 1);
            __syncthreads();
        }
    }

    // epilogue: h1 store + attention dots, fully in-lane (heads 2w and 2w+1)
    float s0 = 0.f, s1 = 0.f, d0 = 0.f, d1 = 0.f;
#pragma unroll
    for (int j = 0; j < 8; j++) {
        s0 = fmaf(acc[j],     att_src[c0 + j],     s0);
        d0 = fmaf(acc[j],     att_dst[c0 + j],     d0);
        s1 = fmaf(acc[8 + j], att_src[c0 + 8 + j], s1);
        d1 = fmaf(acc[8 + j], att_dst[c0 + 8 + j], d1);
    }
    if (valid) {
#pragma unroll
        for (int t = 0; t < 4; t++)
            *(float4*)(h1 + (size_t)gr * HC1 + c0 + 4 * t) =
                make_float4(acc[4 * t], acc[4 * t + 1], acc[4 * t + 2], acc[4 * t + 3]);
        const int h0 = wid * 2;
        a_src[gr * H1H + h0]     = s0;
        a_src[gr * H1H + h0 + 1] = s1;
        a_dst[gr * H1H + h0]     = d0;
        a_dst[gr * H1H + h0 + 1] = d1;
    }
}

// ---------------- CSR build, bucketed (R2 config) ----------------
__global__ __launch_bounds__(256) void k_bcnt(const int* __restrict__ dst, int E,
                                              int* __restrict__ gcnt) {
    __shared__ int lcnt[NBUK];
    for (int i = threadIdx.x; i < NBUK; i += 256) lcnt[i] = 0;
    __syncthreads();
    const int e0 = blockIdx.x * EPB;
#pragma unroll
    for (int i = 0; i < EPB / 256; i++) {
        const int e = e0 + i * 256 + threadIdx.x;
        if (e < E) atomicAdd(&lcnt[dst[e] >> 8], 1);
    }
    __syncthreads();
    for (int i = threadIdx.x; i < NBUK; i += 256)
        if (lcnt[i]) atomicAdd(&gcnt[i], lcnt[i]);
}

__global__ __launch_bounds__(512) void k_bscan(const int* __restrict__ gcnt,
                                               int* __restrict__ gbase,
                                               int* __restrict__ gcur, int E) {
    __shared__ int sm[512];
    const int t = threadIdx.x;
    const int v = (t < NBUK) ? gcnt[t] : 0;
    sm[t] = v;
    __syncthreads();
    for (int off = 1; off < 512; off <<= 1) {
        const int u = (t >= off) ? sm[t - off] : 0;
        __syncthreads();
        sm[t] += u;
        __syncthreads();
    }
    if (t < NBUK) {
        const int b = sm[t] - v;
        gbase[t] = b;
        gcur[t]  = b;
    }
    if (t == 0) gbase[NBUK] = E;
}

__global__ __launch_bounds__(256) void k_bfill(const int* __restrict__ src,
                                               const int* __restrict__ dst, int E,
                                               int* __restrict__ gcur,
                                               int2* __restrict__ pairs) {
    __shared__ int lcnt[NBUK];
    __shared__ int lbase[NBUK];
    for (int i = threadIdx.x; i < NBUK; i += 256) lcnt[i] = 0;
    __syncthreads();
    const int e0 = blockIdx.x * EPB;
#pragma unroll
    for (int i = 0; i < EPB / 256; i++) {
        const int e = e0 + i * 256 + threadIdx.x;
        if (e < E) atomicAdd(&lcnt[dst[e] >> 8], 1);
    }
    __syncthreads();
    for (int i = threadIdx.x; i < NBUK; i += 256)
        lbase[i] = lcnt[i] ? atomicAdd(&gcur[i], lcnt[i]) : 0;
    __syncthreads();
#pragma unroll
    for (int i = 0; i < EPB / 256; i++) {
        const int e = e0 + i * 256 + threadIdx.x;
        if (e < E) {
            const int d = dst[e];
            const int pos = atomicAdd(&lbase[d >> 8], 1);
            pairs[pos] = make_int2(src[e], d);
        }
    }
}

__global__ __launch_bounds__(256) void k_bscatter(const int2* __restrict__ pairs,
                                                  const int* __restrict__ gbase,
                                                  int* __restrict__ offs,
                                                  int* __restrict__ srcsort, int E) {
    __shared__ int ldeg[NPB];
    __shared__ int ltmp[NPB];
    __shared__ int lcur[NPB];
    const int b = blockIdx.x;
    const int tx = threadIdx.x;
    const int node0 = b << 8;
    const int pbeg = gbase[b];
    const int cnt  = gbase[b + 1] - pbeg;

    ldeg[tx] = 0;
    __syncthreads();
    for (int i = tx; i < cnt; i += 256)
        atomicAdd(&ldeg[pairs[pbeg + i].y - node0], 1);
    __syncthreads();
    const int v = ldeg[tx];
    ltmp[tx] = v;
    __syncthreads();
    for (int off = 1; off < 256; off <<= 1) {
        const int u = (tx >= off) ? ltmp[tx - off] : 0;
        __syncthreads();
        ltmp[tx] += u;
        __syncthreads();
    }
    const int mypos = pbeg + ltmp[tx] - v;
    if (node0 + tx < N_NODES) offs[node0 + tx] = mypos;
    lcur[tx] = mypos;
    if (b == NBUK - 1 && tx == 0) offs[N_NODES] = E;
    __syncthreads();
    for (int i = tx; i < cnt; i += 256) {
        const int2 p = pairs[pbeg + i];
        const int pos = atomicAdd(&lcur[p.y - node0], 1);
        srcsort[pos] = p.x;
    }
}

// ---------------- Layer-1: single-pass batched online softmax + aggregate ----------------
__global__ __launch_bounds__(256) void k_agg1(const float* __restrict__ h1,
                                              const float* __restrict__ a_src,
                                              const float* __restrict__ a_dst,
                                              const int* __restrict__ offs,
                                              const int* __restrict__ srcsort,
                                              const float* __restrict__ b1,
                                              float* __restrict__ h1e) {
    const int n = blockIdx.x * 4 + (threadIdx.x >> 6);
    if (n >= N_NODES) return;
    const int lane = threadIdx.x & 63;
    const int hh   = lane >> 3;
    const float adn = a_dst[n * H1H + hh];
    const int beg = offs[n], end = offs[n + 1];

    float e0 = a_src[n * H1H + hh] + adn;
    e0 = e0 > 0.f ? e0 : NEG_SLOPE * e0;
    float m = e0;
    float denom = 1.f;
    float acc = h1[(size_t)n * HC1 + lane];

    int j = beg;
    for (; j + 8 <= end; j += 8) {
        int s[8];
#pragma unroll
        for (int t = 0; t < 8; t++) s[t] = srcsort[j + t];
        float q[8], g[8];
#pragma unroll
        for (int t = 0; t < 8; t++) q[t] = a_src[s[t] * H1H + hh];
#pragma unroll
        for (int t = 0; t < 8; t++) g[t] = h1[(size_t)s[t] * HC1 + lane];
        float f[8];
#pragma unroll
        for (int t = 0; t < 8; t++) {
            const float e = q[t] + adn;
            f[t] = e > 0.f ? e : NEG_SLOPE * e;
        }
        const float cm = fmaxf(fmaxf(fmaxf(f[0], f[1]), fmaxf(f[2], f[3])),
                               fmaxf(fmaxf(f[4], f[5]), fmaxf(f[6], f[7])));
        const float nm = fmaxf(m, cm);
        const float sc = __expf(m - nm);
        float w[8];
#pragma unroll
        for (int t = 0; t < 8; t++) w[t] = __expf(f[t] - nm);
        const float wsum = ((w[0] + w[1]) + (w[2] + w[3])) + ((w[4] + w[5]) + (w[6] + w[7]));
        const float wg = fmaf(w[0], g[0], fmaf(w[1], g[1], fmaf(w[2], g[2], fmaf(w[3], g[3],
                         fmaf(w[4], g[4], fmaf(w[5], g[5], fmaf(w[6], g[6], w[7] * g[7])))))));
        denom = fmaf(denom, sc, wsum);
        acc = fmaf(acc, sc, wg);
        m = nm;
    }
    for (; j + 4 <= end; j += 4) {
        const int s0 = srcsort[j], s1 = srcsort[j + 1];
        const int s2 = srcsort[j + 2], s3 = srcsort[j + 3];
        const float q0 = a_src[s0 * H1H + hh], q1 = a_src[s1 * H1H + hh];
        const float q2 = a_src[s2 * H1H + hh], q3 = a_src[s3 * H1H + hh];
        const float g0 = h1[(size_t)s0 * HC1 + lane];
        const float g1 = h1[(size_t)s1 * HC1 + lane];
        const float g2 = h1[(size_t)s2 * HC1 + lane];
        const float g3 = h1[(size_t)s3 * HC1 + lane];
        float f0 = q0 + adn; f0 = f0 > 0.f ? f0 : NEG_SLOPE * f0;
        float f1 = q1 + adn; f1 = f1 > 0.f ? f1 : NEG_SLOPE * f1;
        float f2 = q2 + adn; f2 = f2 > 0.f ? f2 : NEG_SLOPE * f2;
        float f3 = q3 + adn; f3 = f3 > 0.f ? f3 : NEG_SLOPE * f3;
        const float nm = fmaxf(m, fmaxf(fmaxf(f0, f1), fmaxf(f2, f3)));
        const float sc = __expf(m - nm);
        const float w0 = __expf(f0 - nm), w1 = __expf(f1 - nm);
        const float w2 = __expf(f2 - nm), w3 = __expf(f3 - nm);
        denom = fmaf(denom, sc, (w0 + w1) + (w2 + w3));
        acc = fmaf(acc, sc, fmaf(w0, g0, fmaf(w1, g1, fmaf(w2, g2, w3 * g3))));
        m = nm;
    }
    for (; j < end; j++) {
        const int s = srcsort[j];
        float e = a_src[s * H1H + hh] + adn;
        e = e > 0.f ? e : NEG_SLOPE * e;
        const float g = h1[(size_t)s * HC1 + lane];
        const float nm = fmaxf(m, e);
        const float sc = __expf(m - nm);
        const float w = __expf(e - nm);
        denom = fmaf(denom, sc, w);
        acc = fmaf(acc, sc, w * g);
        m = nm;
    }
    float v = acc / denom + b1[lane];
    h1e[(size_t)n * HC1 + lane] = v > 0.f ? v : (__expf(v) - 1.f);
}

// ---------------- Layer-2 GEMM (64->40), LDS-tiled, + fused attention dots ----
#define TM2 128
__global__ __launch_bounds__(256) void k_gemm2(const float* __restrict__ h1e,
                                               const float* __restrict__ W2,
                                               const float* __restrict__ att_src2,
                                               const float* __restrict__ att_dst2,
                                               float* __restrict__ h2,
                                               float* __restrict__ a_src2,
                                               float* __restrict__ a_dst2) {
    __shared__ float hs[32][65][4];   // [node_group][k(+pad)][node_in_group]
    __shared__ float w2t[NCLS][68];   // transposed W2, padded
    __shared__ float asv[NCLS], adv[NCLS];
    const int tx = threadIdx.x;
    const int node0 = blockIdx.x * TM2;

    for (int f = tx; f < HC1 * NCLS; f += 256) {
        const int k = f / NCLS, c = f - k * NCLS;
        w2t[c][k] = W2[f];
    }
    if (tx < NCLS) {
        asv[tx] = att_src2[tx];
        adv[tx] = att_dst2[tx];
    }
#pragma unroll
    for (int i = 0; i < 8; i++) {
        const int f  = tx + 256 * i;      // 2048 float4 = 128 rows x 16
        const int n  = f >> 4;
        const int k4 = (f & 15) << 2;
        const int gn = node0 + n;
        const float4 v = (gn < N_NODES) ? *(const float4*)(h1e + (size_t)gn * HC1 + k4)
                                        : make_float4(0.f, 0.f, 0.f, 0.f);
        const int ng = n >> 2, ni = n & 3;
        hs[ng][k4 + 0][ni] = v.x;
        hs[ng][k4 + 1][ni] = v.y;
        hs[ng][k4 + 2][ni] = v.z;
        hs[ng][k4 + 3][ni] = v.w;
    }
    __syncthreads();

    const int ng = tx >> 3;          // 0..31 -> nodes ng*4..ng*4+3
    const int cg = tx & 7;           // 0..7  -> classes cg*5..cg*5+4
    const int c0 = cg * 5;

    float acc[4][5];
#pragma unroll
    for (int i = 0; i < 4; i++)
#pragma unroll
        for (int j = 0; j < 5; j++) acc[i][j] = 0.f;

    for (int k = 0; k < HC1; k += 4) {
        float4 hv[4];
#pragma unroll
        for (int t = 0; t < 4; t++) hv[t] = *(const float4*)&hs[ng][k + t][0];
#pragma unroll
        for (int j = 0; j < 5; j++) {
            const float4 wv = *(const float4*)&w2t[c0 + j][k];
            acc[0][j] = fmaf(hv[0].x, wv.x, fmaf(hv[1].x, wv.y, fmaf(hv[2].x, wv.z, fmaf(hv[3].x, wv.w, acc[0][j]))));
            acc[1][j] = fmaf(hv[0].y, wv.x, fmaf(hv[1].y, wv.y, fmaf(hv[2].y, wv.z, fmaf(hv[3].y, wv.w, acc[1][j]))));
            acc[2][j] = fmaf(hv[0].z, wv.x, fmaf(hv[1].z, wv.y, fmaf(hv[2].z, wv.z, fmaf(hv[3].z, wv.w, acc[2][j]))));
            acc[3][j] = fmaf(hv[0].w, wv.x, fmaf(hv[1].w, wv.y, fmaf(hv[2].w, wv.z, fmaf(hv[3].w, wv.w, acc[3][j]))));
        }
    }

    // store h2 + fused att dots (reduce partials over the 8 cg lanes)
    float ps[4], pd[4];
#pragma unroll
    for (int i = 0; i < 4; i++) {
        const int gn = node0 + ng * 4 + i;
        float s = 0.f, d = 0.f;
#pragma unroll
        for (int j = 0; j < 5; j++) {
            s = fmaf(acc[i][j], asv[c0 + j], s);
            d = fmaf(acc[i][j], adv[c0 + j], d);
        }
        ps[i] = s;
        pd[i] = d;
        if (gn < N_NODES) {
#pragma unroll
            for (int j = 0; j < 5; j++)
                h2[(size_t)gn * NCLS + c0 + j] = acc[i][j];
        }
    }
#pragma unroll
    for (int off = 1; off < 8; off <<= 1) {
#pragma unroll
        for (int i = 0; i < 4; i++) {
            ps[i] += __shfl_xor(ps[i], off, 64);
            pd[i] += __shfl_xor(pd[i], off, 64);
        }
    }
    if (cg == 0) {
#pragma unroll
        for (int i = 0; i < 4; i++) {
            const int gn = node0 + ng * 4 + i;
            if (gn < N_NODES) {
                a_src2[gn] = ps[i];
                a_dst2[gn] = pd[i];
            }
        }
    }
}

// ---------------- Layer-2: single-pass online softmax-aggregate + class softmax ----------------
__global__ __launch_bounds__(256) void k_agg2(const float* __restrict__ h2,
                                              const float* __restrict__ a_src,
                                              const float* __restrict__ a_dst,
                                              const int* __restrict__ offs,
                                              const int* __restrict__ srcsort,
                                              const float* __restrict__ b2,
                                              float* __restrict__ out) {
    const int n = blockIdx.x * 4 + (threadIdx.x >> 6);
    if (n >= N_NODES) return;
    const int lane = threadIdx.x & 63;
    const float adn = a_dst[n];
    const int beg = offs[n], end = offs[n + 1];

    float e0 = a_src[n] + adn;
    e0 = e0 > 0.f ? e0 : NEG_SLOPE * e0;
    float m = e0;
    float denom = 1.f;
    float acc = (lane < NCLS) ? h2[(size_t)n * NCLS + lane] : 0.f;

    int j = beg;
    for (; j + 8 <= end; j += 8) {
        int s[8];
#pragma unroll
        for (int t = 0; t < 8; t++) s[t] = srcsort[j + t];
        float q[8], g[8];
#pragma unroll
        for (int t = 0; t < 8; t++) q[t] = a_src[s[t]];
#pragma unroll
        for (int t = 0; t < 8; t++)
            g[t] = (lane < NCLS) ? h2[(size_t)s[t] * NCLS + lane] : 0.f;
        float f[8];
#pragma unroll
        for (int t = 0; t < 8; t++) {
            const float e = q[t] + adn;
            f[t] = e > 0.f ? e : NEG_SLOPE * e;
        }
        const float cm = fmaxf(fmaxf(fmaxf(f[0], f[1]), fmaxf(f[2], f[3])),
                               fmaxf(fmaxf(f[4], f[5]), fmaxf(f[6], f[7])));
        const float nm = fmaxf(m, cm);
        const float sc = __expf(m - nm);
        float w[8];
#pragma unroll
        for (int t = 0; t < 8; t++) w[t] = __expf(f[t] - nm);
        const float wsum = ((w[0] + w[1]) + (w[2] + w[3])) + ((w[4] + w[5]) + (w[6] + w[7]));
        const float wg = fmaf(w[0], g[0], fmaf(w[1], g[1], fmaf(w[2], g[2], fmaf(w[3], g[3],
                         fmaf(w[4], g[4], fmaf(w[5], g[5], fmaf(w[6], g[6], w[7] * g[7])))))));
        denom = fmaf(denom, sc, wsum);
        acc = fmaf(acc, sc, wg);
        m = nm;
    }
    for (; j + 4 <= end; j += 4) {
        const int s0 = srcsort[j], s1 = srcsort[j + 1];
        const int s2 = srcsort[j + 2], s3 = srcsort[j + 3];
        const float q0 = a_src[s0], q1 = a_src[s1];
        const float q2 = a_src[s2], q3 = a_src[s3];
        float g0 = 0.f, g1 = 0.f, g2 = 0.f, g3 = 0.f;
        if (lane < NCLS) {
            g0 = h2[(size_t)s0 * NCLS + lane];
            g1 = h2[(size_t)s1 * NCLS + lane];
            g2 = h2[(size_t)s2 * NCLS + lane];
            g3 = h2[(size_t)s3 * NCLS + lane];
        }
        float f0 = q0 + adn; f0 = f0 > 0.f ? f0 : NEG_SLOPE * f0;
        float f1 = q1 + adn; f1 = f1 > 0.f ? f1 : NEG_SLOPE * f1;
        float f2 = q2 + adn; f2 = f2 > 0.f ? f2 : NEG_SLOPE * f2;
        float f3 = q3 + adn; f3 = f3 > 0.f ? f3 : NEG_SLOPE * f3;
        const float nm = fmaxf(m, fmaxf(fmaxf(f0, f1), fmaxf(f2, f3)));
        const float sc = __expf(m - nm);
        const float w0 = __expf(f0 - nm), w1 = __expf(f1 - nm);
        const float w2 = __expf(f2 - nm), w3 = __expf(f3 - nm);
        denom = fmaf(denom, sc, (w0 + w1) + (w2 + w3));
        acc = fmaf(acc, sc, fmaf(w0, g0, fmaf(w1, g1, fmaf(w2, g2, w3 * g3))));
        m = nm;
    }
    for (; j < end; j++) {
        const int s = srcsort[j];
        float e = a_src[s] + adn;
        e = e > 0.f ? e : NEG_SLOPE * e;
        const float g = (lane < NCLS) ? h2[(size_t)s * NCLS + lane] : 0.f;
        const float nm = fmaxf(m, e);
        const float sc = __expf(m - nm);
        const float w = __expf(e - nm);
        denom = fmaf(denom, sc, w);
        acc = fmaf(acc, sc, w * g);
        m = nm;
    }
    float o = (lane < NCLS) ? (acc / denom + b2[lane]) : -INFINITY;
    float mx = o;
#pragma unroll
    for (int off = 32; off; off >>= 1) mx = fmaxf(mx, __shfl_xor(mx, off, 64));
    const float ex = (lane < NCLS) ? __expf(o - mx) : 0.f;
    float sm = ex;
#pragma unroll
    for (int off = 32; off; off >>= 1) sm += __shfl_xor(sm, off, 64);
    if (lane < NCLS) out[(size_t)n * NCLS + lane] = ex / sm;
}

// ---------------- launcher ----------------
extern "C" void kernel_launch(void* const* d_in, const int* in_sizes, int n_in,
                              void* d_out, int out_size, void* d_ws, size_t ws_size,
                              hipStream_t stream) {
    const float* x   = (const float*)d_in[0];
    const int*   ei  = (const int*)d_in[1];
    const float* W1v = (const float*)d_in[2];
    const float* as1 = (const float*)d_in[3];
    const float* ad1 = (const float*)d_in[4];
    const float* b1  = (const float*)d_in[5];
    const float* W2v = (const float*)d_in[6];
    const float* as2 = (const float*)d_in[7];
    const float* ad2 = (const float*)d_in[8];
    const float* b2  = (const float*)d_in[9];
    const int E = in_sizes[1] / 2;
    const int* esrc = ei;
    const int* edst = ei + E;

    char* wp = (char*)d_ws;
    auto alloc = [&](size_t bytes) {
        char* p = wp;
        wp += (bytes + 255) & ~(size_t)255;
        return p;
    };
    float* h1     = (float*)alloc((size_t)N_NODES * HC1 * 4);
    float* h1e    = (float*)alloc((size_t)N_NODES * HC1 * 4);
    float* a_src1 = (float*)alloc((size_t)N_NODES * H1H * 4);
    float* a_dst1 = (float*)alloc((size_t)N_NODES * H1H * 4);
    float* a_src2 = (float*)alloc((size_t)N_NODES * 4);
    float* a_dst2 = (float*)alloc((size_t)N_NODES * 4);
    int*   offs   = (int*)alloc((size_t)(N_NODES + 1) * 4);
    int*   gcnt   = (int*)alloc((size_t)NBUK * 4);
    int*   gbase  = (int*)alloc((size_t)(NBUK + 1) * 4);
    int*   gcur   = (int*)alloc((size_t)NBUK * 4);
    int*   srcsort= (int*)alloc((size_t)E * 4);
    int2*  pairs  = (int2*)alloc((size_t)E * 8);
    float* h2     = h1;  // h1 dead after k_agg1; reuse for h2

    hipMemsetAsync(gcnt, 0, (size_t)NBUK * 4, stream);

    const int NEB = (E + EPB - 1) / EPB;
    k_gemm1<<<(N_NODES + TM - 1) / TM, 256, 0, stream>>>(x, W1v, as1, ad1, h1, a_src1, a_dst1);
    k_bcnt<<<NEB, 256, 0, stream>>>(edst, E, gcnt);
    k_bscan<<<1, 512, 0, stream>>>(gcnt, gbase, gcur, E);
    k_bfill<<<NEB, 256, 0, stream>>>(esrc, edst, E, gcur, pairs);
    k_bscatter<<<NBUK, 256, 0, stream>>>(pairs, gbase, offs, srcsort, E);
    k_agg1<<<(N_NODES + 3) / 4, 256, 0, stream>>>(h1, a_src1, a_dst1, offs, srcsort, b1, h1e);
    k_gemm2<<<(N_NODES + TM2 - 1) / TM2, 256, 0, stream>>>(h1e, W2v, as2, ad2, h2, a_src2, a_dst2);
    k_agg2<<<(N_NODES + 3) / 4, 256, 0, stream>>>(h2, a_src2, a_dst2, offs, srcsort, b2, (float*)d_out);
}

// Round 6
// 654.910 us; speedup vs baseline: 1.0096x; 1.0096x over previous
//
#include <hip/hip_runtime.h>
#include <math.h>

#define N_NODES 100000
#define FIN     512
#define H1H     8
#define C1C     8
#define HC1     64
#define NCLS    40
#define NEG_SLOPE 0.2f

// CSR bucketing: 256 dst-nodes per bucket (R2 config, best known)
#define NPB   256
#define NBUK  391          // ceil(100000/256)
#define EPB   4096         // edges per block in bucket count/fill

// ---------------- Layer-1 GEMM + fused attention dots (R6: 16x8 tile) -------
// LDS-throughput model: bytes = N*512*64*4*(1/R+1/C).  8x4 tile -> 4.9GB ->
// 94us ideal (measured 120).  16x8 -> 2.46GB -> ~47us ideal.
// 128 thr/block (2 waves), TM=256, BK=8 double-buffered.
// x rows stored padded: row' = row + (row>>4)*4 -> per-wave b128 bank bases
// {0,20,8,28,16,4,24,12} all distinct -> conflict-free.
#define TM 256
#define BK 8
#define XSW 320            // padded row-dim width (max row' = 315)

__global__ __launch_bounds__(128) void k_gemm1(const float* __restrict__ x,
                                               const float* __restrict__ W1,
                                               const float* __restrict__ att_src,
                                               const float* __restrict__ att_dst,
                                               float* __restrict__ h1,
                                               float* __restrict__ a_src,
                                               float* __restrict__ a_dst) {
    __shared__ float xs[2][BK][XSW];
    __shared__ float ws[2][BK][68];
    const int t = threadIdx.x;
    const int row_base = blockIdx.x * TM;
    const int rg = t >> 3;            // 0..15 -> rows rg*16..rg*16+15
    const int cg = t & 7;             // 0..7  -> cols cg*8..cg*8+7 (= head cg)
    const int xbase = rg * 20;        // row' of first owned row (16 contig words)

    // staging indices: x = 512 float4 (256 rows x 2), 4 per thread
    int srow[4], skq[4];
#pragma unroll
    for (int i = 0; i < 4; i++) {
        const int f = t + 128 * i;
        srow[i] = f >> 1;
        skq[i]  = (f & 1) << 2;
    }
    const int wkk = t >> 4;           // 0..7
    const int wc4 = (t & 15) << 2;    // 0..60

    float4 xr4[4];
    float4 wr4;
    auto load_regs = [&](int k0) {
#pragma unroll
        for (int i = 0; i < 4; i++) {
            const int gr = row_base + srow[i];
            xr4[i] = (gr < N_NODES) ? *(const float4*)(x + (size_t)gr * FIN + k0 + skq[i])
                                    : make_float4(0.f, 0.f, 0.f, 0.f);
        }
        wr4 = *(const float4*)(W1 + (size_t)(k0 + wkk) * HC1 + wc4);
    };
    auto store_lds = [&](int buf) {
#pragma unroll
        for (int i = 0; i < 4; i++) {
            const int rp = srow[i] + ((srow[i] >> 4) << 2);
            xs[buf][skq[i] + 0][rp] = xr4[i].x;
            xs[buf][skq[i] + 1][rp] = xr4[i].y;
            xs[buf][skq[i] + 2][rp] = xr4[i].z;
            xs[buf][skq[i] + 3][rp] = xr4[i].w;
        }
        *(float4*)&ws[buf][wkk][wc4] = wr4;
    };

    float acc[16][8];
#pragma unroll
    for (int i = 0; i < 16; i++)
#pragma unroll
        for (int j = 0; j < 8; j++) acc[i][j] = 0.f;

    load_regs(0);
    store_lds(0);
    __syncthreads();

    int buf = 0;
    for (int k0 = 0; k0 < FIN; k0 += BK, buf ^= 1) {
        const bool more = (k0 + BK < FIN);
        if (more) load_regs(k0 + BK);
#pragma unroll
        for (int k = 0; k < BK; k++) {
            const float4 xa0 = *(const float4*)&xs[buf][k][xbase];
            const float4 xa1 = *(const float4*)&xs[buf][k][xbase + 4];
            const float4 xa2 = *(const float4*)&xs[buf][k][xbase + 8];
            const float4 xa3 = *(const float4*)&xs[buf][k][xbase + 12];
            const float4 wv0 = *(const float4*)&ws[buf][k][cg * 8];
            const float4 wv1 = *(const float4*)&ws[buf][k][cg * 8 + 4];
            const float xr[16] = {xa0.x, xa0.y, xa0.z, xa0.w,
                                  xa1.x, xa1.y, xa1.z, xa1.w,
                                  xa2.x, xa2.y, xa2.z, xa2.w,
                                  xa3.x, xa3.y, xa3.z, xa3.w};
            const float wr[8] = {wv0.x, wv0.y, wv0.z, wv0.w,
                                 wv1.x, wv1.y, wv1.z, wv1.w};
#pragma unroll
            for (int i = 0; i < 16; i++)
#pragma unroll
                for (int j = 0; j < 8; j++)
                    acc[i][j] = fmaf(xr[i], wr[j], acc[i][j]);
        }
        if (more) {
            store_lds(buf ^ 1);
            __syncthreads();
        }
    }

    // epilogue: cols cg*8..+7 = head cg exactly -> dots fully in-lane
    float asv[8], adv[8];
#pragma unroll
    for (int j = 0; j < 8; j++) {
        asv[j] = att_src[cg * 8 + j];
        adv[j] = att_dst[cg * 8 + j];
    }
#pragma unroll
    for (int i = 0; i < 16; i++) {
        const int gr = row_base + rg * 16 + i;
        if (gr < N_NODES) {
            *(float4*)(h1 + (size_t)gr * HC1 + cg * 8) =
                make_float4(acc[i][0], acc[i][1], acc[i][2], acc[i][3]);
            *(float4*)(h1 + (size_t)gr * HC1 + cg * 8 + 4) =
                make_float4(acc[i][4], acc[i][5], acc[i][6], acc[i][7]);
            float s = 0.f, d = 0.f;
#pragma unroll
            for (int j = 0; j < 8; j++) {
                s = fmaf(acc[i][j], asv[j], s);
                d = fmaf(acc[i][j], adv[j], d);
            }
            a_src[gr * H1H + cg] = s;
            a_dst[gr * H1H + cg] = d;
        }
    }
}

// ---------------- CSR build, bucketed (R2 config) ----------------
__global__ __launch_bounds__(256) void k_bcnt(const int* __restrict__ dst, int E,
                                              int* __restrict__ gcnt) {
    __shared__ int lcnt[NBUK];
    for (int i = threadIdx.x; i < NBUK; i += 256) lcnt[i] = 0;
    __syncthreads();
    const int e0 = blockIdx.x * EPB;
#pragma unroll
    for (int i = 0; i < EPB / 256; i++) {
        const int e = e0 + i * 256 + threadIdx.x;
        if (e < E) atomicAdd(&lcnt[dst[e] >> 8], 1);
    }
    __syncthreads();
    for (int i = threadIdx.x; i < NBUK; i += 256)
        if (lcnt[i]) atomicAdd(&gcnt[i], lcnt[i]);
}

__global__ __launch_bounds__(512) void k_bscan(const int* __restrict__ gcnt,
                                               int* __restrict__ gbase,
                                               int* __restrict__ gcur, int E) {
    __shared__ int sm[512];
    const int t = threadIdx.x;
    const int v = (t < NBUK) ? gcnt[t] : 0;
    sm[t] = v;
    __syncthreads();
    for (int off = 1; off < 512; off <<= 1) {
        const int u = (t >= off) ? sm[t - off] : 0;
        __syncthreads();
        sm[t] += u;
        __syncthreads();
    }
    if (t < NBUK) {
        const int b = sm[t] - v;
        gbase[t] = b;
        gcur[t]  = b;
    }
    if (t == 0) gbase[NBUK] = E;
}

__global__ __launch_bounds__(256) void k_bfill(const int* __restrict__ src,
                                               const int* __restrict__ dst, int E,
                                               int* __restrict__ gcur,
                                               int2* __restrict__ pairs) {
    __shared__ int lcnt[NBUK];
    __shared__ int lbase[NBUK];
    for (int i = threadIdx.x; i < NBUK; i += 256) lcnt[i] = 0;
    __syncthreads();
    const int e0 = blockIdx.x * EPB;
#pragma unroll
    for (int i = 0; i < EPB / 256; i++) {
        const int e = e0 + i * 256 + threadIdx.x;
        if (e < E) atomicAdd(&lcnt[dst[e] >> 8], 1);
    }
    __syncthreads();
    for (int i = threadIdx.x; i < NBUK; i += 256)
        lbase[i] = lcnt[i] ? atomicAdd(&gcur[i], lcnt[i]) : 0;
    __syncthreads();
#pragma unroll
    for (int i = 0; i < EPB / 256; i++) {
        const int e = e0 + i * 256 + threadIdx.x;
        if (e < E) {
            const int d = dst[e];
            const int pos = atomicAdd(&lbase[d >> 8], 1);
            pairs[pos] = make_int2(src[e], d);
        }
    }
}

__global__ __launch_bounds__(256) void k_bscatter(const int2* __restrict__ pairs,
                                                  const int* __restrict__ gbase,
                                                  int* __restrict__ offs,
                                                  int* __restrict__ srcsort, int E) {
    __shared__ int ldeg[NPB];
    __shared__ int ltmp[NPB];
    __shared__ int lcur[NPB];
    const int b = blockIdx.x;
    const int tx = threadIdx.x;
    const int node0 = b << 8;
    const int pbeg = gbase[b];
    const int cnt  = gbase[b + 1] - pbeg;

    ldeg[tx] = 0;
    __syncthreads();
    for (int i = tx; i < cnt; i += 256)
        atomicAdd(&ldeg[pairs[pbeg + i].y - node0], 1);
    __syncthreads();
    const int v = ldeg[tx];
    ltmp[tx] = v;
    __syncthreads();
    for (int off = 1; off < 256; off <<= 1) {
        const int u = (tx >= off) ? ltmp[tx - off] : 0;
        __syncthreads();
        ltmp[tx] += u;
        __syncthreads();
    }
    const int mypos = pbeg + ltmp[tx] - v;
    if (node0 + tx < N_NODES) offs[node0 + tx] = mypos;
    lcur[tx] = mypos;
    if (b == NBUK - 1 && tx == 0) offs[N_NODES] = E;
    __syncthreads();
    for (int i = tx; i < cnt; i += 256) {
        const int2 p = pairs[pbeg + i];
        const int pos = atomicAdd(&lcur[p.y - node0], 1);
        srcsort[pos] = p.x;
    }
}

// ---------------- Layer-1: single-pass batched online softmax + aggregate ----------------
__global__ __launch_bounds__(256) void k_agg1(const float* __restrict__ h1,
                                              const float* __restrict__ a_src,
                                              const float* __restrict__ a_dst,
                                              const int* __restrict__ offs,
                                              const int* __restrict__ srcsort,
                                              const float* __restrict__ b1,
                                              float* __restrict__ h1e) {
    const int n = blockIdx.x * 4 + (threadIdx.x >> 6);
    if (n >= N_NODES) return;
    const int lane = threadIdx.x & 63;
    const int hh   = lane >> 3;
    const float adn = a_dst[n * H1H + hh];
    const int beg = offs[n], end = offs[n + 1];

    float e0 = a_src[n * H1H + hh] + adn;
    e0 = e0 > 0.f ? e0 : NEG_SLOPE * e0;
    float m = e0;
    float denom = 1.f;
    float acc = h1[(size_t)n * HC1 + lane];

    int j = beg;
    for (; j + 8 <= end; j += 8) {
        int s[8];
#pragma unroll
        for (int t = 0; t < 8; t++) s[t] = srcsort[j + t];
        float q[8], g[8];
#pragma unroll
        for (int t = 0; t < 8; t++) q[t] = a_src[s[t] * H1H + hh];
#pragma unroll
        for (int t = 0; t < 8; t++) g[t] = h1[(size_t)s[t] * HC1 + lane];
        float f[8];
#pragma unroll
        for (int t = 0; t < 8; t++) {
            const float e = q[t] + adn;
            f[t] = e > 0.f ? e : NEG_SLOPE * e;
        }
        const float cm = fmaxf(fmaxf(fmaxf(f[0], f[1]), fmaxf(f[2], f[3])),
                               fmaxf(fmaxf(f[4], f[5]), fmaxf(f[6], f[7])));
        const float nm = fmaxf(m, cm);
        const float sc = __expf(m - nm);
        float w[8];
#pragma unroll
        for (int t = 0; t < 8; t++) w[t] = __expf(f[t] - nm);
        const float wsum = ((w[0] + w[1]) + (w[2] + w[3])) + ((w[4] + w[5]) + (w[6] + w[7]));
        const float wg = fmaf(w[0], g[0], fmaf(w[1], g[1], fmaf(w[2], g[2], fmaf(w[3], g[3],
                         fmaf(w[4], g[4], fmaf(w[5], g[5], fmaf(w[6], g[6], w[7] * g[7])))))));
        denom = fmaf(denom, sc, wsum);
        acc = fmaf(acc, sc, wg);
        m = nm;
    }
    for (; j + 4 <= end; j += 4) {
        const int s0 = srcsort[j], s1 = srcsort[j + 1];
        const int s2 = srcsort[j + 2], s3 = srcsort[j + 3];
        const float q0 = a_src[s0 * H1H + hh], q1 = a_src[s1 * H1H + hh];
        const float q2 = a_src[s2 * H1H + hh], q3 = a_src[s3 * H1H + hh];
        const float g0 = h1[(size_t)s0 * HC1 + lane];
        const float g1 = h1[(size_t)s1 * HC1 + lane];
        const float g2 = h1[(size_t)s2 * HC1 + lane];
        const float g3 = h1[(size_t)s3 * HC1 + lane];
        float f0 = q0 + adn; f0 = f0 > 0.f ? f0 : NEG_SLOPE * f0;
        float f1 = q1 + adn; f1 = f1 > 0.f ? f1 : NEG_SLOPE * f1;
        float f2 = q2 + adn; f2 = f2 > 0.f ? f2 : NEG_SLOPE * f2;
        float f3 = q3 + adn; f3 = f3 > 0.f ? f3 : NEG_SLOPE * f3;
        const float nm = fmaxf(m, fmaxf(fmaxf(f0, f1), fmaxf(f2, f3)));
        const float sc = __expf(m - nm);
        const float w0 = __expf(f0 - nm), w1 = __expf(f1 - nm);
        const float w2 = __expf(f2 - nm), w3 = __expf(f3 - nm);
        denom = fmaf(denom, sc, (w0 + w1) + (w2 + w3));
        acc = fmaf(acc, sc, fmaf(w0, g0, fmaf(w1, g1, fmaf(w2, g2, w3 * g3))));
        m = nm;
    }
    for (; j < end; j++) {
        const int s = srcsort[j];
        float e = a_src[s * H1H + hh] + adn;
        e = e > 0.f ? e : NEG_SLOPE * e;
        const float g = h1[(size_t)s * HC1 + lane];
        const float nm = fmaxf(m, e);
        const float sc = __expf(m - nm);
        const float w = __expf(e - nm);
        denom = fmaf(denom, sc, w);
        acc = fmaf(acc, sc, w * g);
        m = nm;
    }
    float v = acc / denom + b1[lane];
    h1e[(size_t)n * HC1 + lane] = v > 0.f ? v : (__expf(v) - 1.f);
}

// ---------------- Layer-2 GEMM (64->40), LDS-tiled, + fused attention dots ----
#define TM2 128
__global__ __launch_bounds__(256) void k_gemm2(const float* __restrict__ h1e,
                                               const float* __restrict__ W2,
                                               const float* __restrict__ att_src2,
                                               const float* __restrict__ att_dst2,
                                               float* __restrict__ h2,
                                               float* __restrict__ a_src2,
                                               float* __restrict__ a_dst2) {
    __shared__ float hs[32][65][4];   // [node_group][k(+pad)][node_in_group]
    __shared__ float w2t[NCLS][68];   // transposed W2, padded
    __shared__ float asv[NCLS], adv[NCLS];
    const int tx = threadIdx.x;
    const int node0 = blockIdx.x * TM2;

    for (int f = tx; f < HC1 * NCLS; f += 256) {
        const int k = f / NCLS, c = f - k * NCLS;
        w2t[c][k] = W2[f];
    }
    if (tx < NCLS) {
        asv[tx] = att_src2[tx];
        adv[tx] = att_dst2[tx];
    }
#pragma unroll
    for (int i = 0; i < 8; i++) {
        const int f  = tx + 256 * i;      // 2048 float4 = 128 rows x 16
        const int n  = f >> 4;
        const int k4 = (f & 15) << 2;
        const int gn = node0 + n;
        const float4 v = (gn < N_NODES) ? *(const float4*)(h1e + (size_t)gn * HC1 + k4)
                                        : make_float4(0.f, 0.f, 0.f, 0.f);
        const int ng = n >> 2, ni = n & 3;
        hs[ng][k4 + 0][ni] = v.x;
        hs[ng][k4 + 1][ni] = v.y;
        hs[ng][k4 + 2][ni] = v.z;
        hs[ng][k4 + 3][ni] = v.w;
    }
    __syncthreads();

    const int ng = tx >> 3;          // 0..31 -> nodes ng*4..ng*4+3
    const int cg = tx & 7;           // 0..7  -> classes cg*5..cg*5+4
    const int c0 = cg * 5;

    float acc[4][5];
#pragma unroll
    for (int i = 0; i < 4; i++)
#pragma unroll
        for (int j = 0; j < 5; j++) acc[i][j] = 0.f;

    for (int k = 0; k < HC1; k += 4) {
        float4 hv[4];
#pragma unroll
        for (int t = 0; t < 4; t++) hv[t] = *(const float4*)&hs[ng][k + t][0];
#pragma unroll
        for (int j = 0; j < 5; j++) {
            const float4 wv = *(const float4*)&w2t[c0 + j][k];
            acc[0][j] = fmaf(hv[0].x, wv.x, fmaf(hv[1].x, wv.y, fmaf(hv[2].x, wv.z, fmaf(hv[3].x, wv.w, acc[0][j]))));
            acc[1][j] = fmaf(hv[0].y, wv.x, fmaf(hv[1].y, wv.y, fmaf(hv[2].y, wv.z, fmaf(hv[3].y, wv.w, acc[1][j]))));
            acc[2][j] = fmaf(hv[0].z, wv.x, fmaf(hv[1].z, wv.y, fmaf(hv[2].z, wv.z, fmaf(hv[3].z, wv.w, acc[2][j]))));
            acc[3][j] = fmaf(hv[0].w, wv.x, fmaf(hv[1].w, wv.y, fmaf(hv[2].w, wv.z, fmaf(hv[3].w, wv.w, acc[3][j]))));
        }
    }

    // store h2 + fused att dots (reduce partials over the 8 cg lanes)
    float ps[4], pd[4];
#pragma unroll
    for (int i = 0; i < 4; i++) {
        const int gn = node0 + ng * 4 + i;
        float s = 0.f, d = 0.f;
#pragma unroll
        for (int j = 0; j < 5; j++) {
            s = fmaf(acc[i][j], asv[c0 + j], s);
            d = fmaf(acc[i][j], adv[c0 + j], d);
        }
        ps[i] = s;
        pd[i] = d;
        if (gn < N_NODES) {
#pragma unroll
            for (int j = 0; j < 5; j++)
                h2[(size_t)gn * NCLS + c0 + j] = acc[i][j];
        }
    }
#pragma unroll
    for (int off = 1; off < 8; off <<= 1) {
#pragma unroll
        for (int i = 0; i < 4; i++) {
            ps[i] += __shfl_xor(ps[i], off, 64);
            pd[i] += __shfl_xor(pd[i], off, 64);
        }
    }
    if (cg == 0) {
#pragma unroll
        for (int i = 0; i < 4; i++) {
            const int gn = node0 + ng * 4 + i;
            if (gn < N_NODES) {
                a_src2[gn] = ps[i];
                a_dst2[gn] = pd[i];
            }
        }
    }
}

// ---------------- Layer-2: single-pass online softmax-aggregate + class softmax ----------------
__global__ __launch_bounds__(256) void k_agg2(const float* __restrict__ h2,
                                              const float* __restrict__ a_src,
                                              const float* __restrict__ a_dst,
                                              const int* __restrict__ offs,
                                              const int* __restrict__ srcsort,
                                              const float* __restrict__ b2,
                                              float* __restrict__ out) {
    const int n = blockIdx.x * 4 + (threadIdx.x >> 6);
    if (n >= N_NODES) return;
    const int lane = threadIdx.x & 63;
    const float adn = a_dst[n];
    const int beg = offs[n], end = offs[n + 1];

    float e0 = a_src[n] + adn;
    e0 = e0 > 0.f ? e0 : NEG_SLOPE * e0;
    float m = e0;
    float denom = 1.f;
    float acc = (lane < NCLS) ? h2[(size_t)n * NCLS + lane] : 0.f;

    int j = beg;
    for (; j + 8 <= end; j += 8) {
        int s[8];
#pragma unroll
        for (int t = 0; t < 8; t++) s[t] = srcsort[j + t];
        float q[8], g[8];
#pragma unroll
        for (int t = 0; t < 8; t++) q[t] = a_src[s[t]];
#pragma unroll
        for (int t = 0; t < 8; t++)
            g[t] = (lane < NCLS) ? h2[(size_t)s[t] * NCLS + lane] : 0.f;
        float f[8];
#pragma unroll
        for (int t = 0; t < 8; t++) {
            const float e = q[t] + adn;
            f[t] = e > 0.f ? e : NEG_SLOPE * e;
        }
        const float cm = fmaxf(fmaxf(fmaxf(f[0], f[1]), fmaxf(f[2], f[3])),
                               fmaxf(fmaxf(f[4], f[5]), fmaxf(f[6], f[7])));
        const float nm = fmaxf(m, cm);
        const float sc = __expf(m - nm);
        float w[8];
#pragma unroll
        for (int t = 0; t < 8; t++) w[t] = __expf(f[t] - nm);
        const float wsum = ((w[0] + w[1]) + (w[2] + w[3])) + ((w[4] + w[5]) + (w[6] + w[7]));
        const float wg = fmaf(w[0], g[0], fmaf(w[1], g[1], fmaf(w[2], g[2], fmaf(w[3], g[3],
                         fmaf(w[4], g[4], fmaf(w[5], g[5], fmaf(w[6], g[6], w[7] * g[7])))))));
        denom = fmaf(denom, sc, wsum);
        acc = fmaf(acc, sc, wg);
        m = nm;
    }
    for (; j + 4 <= end; j += 4) {
        const int s0 = srcsort[j], s1 = srcsort[j + 1];
        const int s2 = srcsort[j + 2], s3 = srcsort[j + 3];
        const float q0 = a_src[s0], q1 = a_src[s1];
        const float q2 = a_src[s2], q3 = a_src[s3];
        float g0 = 0.f, g1 = 0.f, g2 = 0.f, g3 = 0.f;
        if (lane < NCLS) {
            g0 = h2[(size_t)s0 * NCLS + lane];
            g1 = h2[(size_t)s1 * NCLS + lane];
            g2 = h2[(size_t)s2 * NCLS + lane];
            g3 = h2[(size_t)s3 * NCLS + lane];
        }
        float f0 = q0 + adn; f0 = f0 > 0.f ? f0 : NEG_SLOPE * f0;
        float f1 = q1 + adn; f1 = f1 > 0.f ? f1 : NEG_SLOPE * f1;
        float f2 = q2 + adn; f2 = f2 > 0.f ? f2 : NEG_SLOPE * f2;
        float f3 = q3 + adn; f3 = f3 > 0.f ? f3 : NEG_SLOPE * f3;
        const float nm = fmaxf(m, fmaxf(fmaxf(f0, f1), fmaxf(f2, f3)));
        const float sc = __expf(m - nm);
        const float w0 = __expf(f0 - nm), w1 = __expf(f1 - nm);
        const float w2 = __expf(f2 - nm), w3 = __expf(f3 - nm);
        denom = fmaf(denom, sc, (w0 + w1) + (w2 + w3));
        acc = fmaf(acc, sc, fmaf(w0, g0, fmaf(w1, g1, fmaf(w2, g2, w3 * g3))));
        m = nm;
    }
    for (; j < end; j++) {
        const int s = srcsort[j];
        float e = a_src[s] + adn;
        e = e > 0.f ? e : NEG_SLOPE * e;
        const float g = (lane < NCLS) ? h2[(size_t)s * NCLS + lane] : 0.f;
        const float nm = fmaxf(m, e);
        const float sc = __expf(m - nm);
        const float w = __expf(e - nm);
        denom = fmaf(denom, sc, w);
        acc = fmaf(acc, sc, w * g);
        m = nm;
    }
    float o = (lane < NCLS) ? (acc / denom + b2[lane]) : -INFINITY;
    float mx = o;
#pragma unroll
    for (int off = 32; off; off >>= 1) mx = fmaxf(mx, __shfl_xor(mx, off, 64));
    const float ex = (lane < NCLS) ? __expf(o - mx) : 0.f;
    float sm = ex;
#pragma unroll
    for (int off = 32; off; off >>= 1) sm += __shfl_xor(sm, off, 64);
    if (lane < NCLS) out[(size_t)n * NCLS + lane] = ex / sm;
}

// ---------------- launcher ----------------
extern "C" void kernel_launch(void* const* d_in, const int* in_sizes, int n_in,
                              void* d_out, int out_size, void* d_ws, size_t ws_size,
                              hipStream_t stream) {
    const float* x   = (const float*)d_in[0];
    const int*   ei  = (const int*)d_in[1];
    const float* W1v = (const float*)d_in[2];
    const float* as1 = (const float*)d_in[3];
    const float* ad1 = (const float*)d_in[4];
    const float* b1  = (const float*)d_in[5];
    const float* W2v = (const float*)d_in[6];
    const float* as2 = (const float*)d_in[7];
    const float* ad2 = (const float*)d_in[8];
    const float* b2  = (const float*)d_in[9];
    const int E = in_sizes[1] / 2;
    const int* esrc = ei;
    const int* edst = ei + E;

    char* wp = (char*)d_ws;
    auto alloc = [&](size_t bytes) {
        char* p = wp;
        wp += (bytes + 255) & ~(size_t)255;
        return p;
    };
    float* h1     = (float*)alloc((size_t)N_NODES * HC1 * 4);
    float* h1e    = (float*)alloc((size_t)N_NODES * HC1 * 4);
    float* a_src1 = (float*)alloc((size_t)N_NODES * H1H * 4);
    float* a_dst1 = (float*)alloc((size_t)N_NODES * H1H * 4);
    float* a_src2 = (float*)alloc((size_t)N_NODES * 4);
    float* a_dst2 = (float*)alloc((size_t)N_NODES * 4);
    int*   offs   = (int*)alloc((size_t)(N_NODES + 1) * 4);
    int*   gcnt   = (int*)alloc((size_t)NBUK * 4);
    int*   gbase  = (int*)alloc((size_t)(NBUK + 1) * 4);
    int*   gcur   = (int*)alloc((size_t)NBUK * 4);
    int*   srcsort= (int*)alloc((size_t)E * 4);
    int2*  pairs  = (int2*)alloc((size_t)E * 8);
    float* h2     = h1;  // h1 dead after k_agg1; reuse for h2

    hipMemsetAsync(gcnt, 0, (size_t)NBUK * 4, stream);

    const int NEB = (E + EPB - 1) / EPB;
    k_gemm1<<<(N_NODES + TM - 1) / TM, 128, 0, stream>>>(x, W1v, as1, ad1, h1, a_src1, a_dst1);
    k_bcnt<<<NEB, 256, 0, stream>>>(edst, E, gcnt);
    k_bscan<<<1, 512, 0, stream>>>(gcnt, gbase, gcur, E);
    k_bfill<<<NEB, 256, 0, stream>>>(esrc, edst, E, gcur, pairs);
    k_bscatter<<<NBUK, 256, 0, stream>>>(pairs, gbase, offs, srcsort, E);
    k_agg1<<<(N_NODES + 3) / 4, 256, 0, stream>>>(h1, a_src1, a_dst1, offs, srcsort, b1, h1e);
    k_gemm2<<<(N_NODES + TM2 - 1) / TM2, 256, 0, stream>>>(h1e, W2v, as2, ad2, h2, a_src2, a_dst2);
    k_agg2<<<(N_NODES + 3) / 4, 256, 0, stream>>>(h2, a_src2, a_dst2, offs, srcsort, b2, (float*)d_out);
}

// Round 8
// 646.455 us; speedup vs baseline: 1.0228x; 1.0131x over previous
//
#include <hip/hip_runtime.h>
#include <math.h>

#define N_NODES 100000
#define FIN     512
#define H1H     8
#define C1C     8
#define HC1     64
#define NCLS    40
#define NEG_SLOPE 0.2f

// CSR bucketing: 256 dst-nodes per bucket (R2 config, best known)
#define NPB   256
#define NBUK  391          // ceil(100000/256)
#define EPB   4096         // edges per block in bucket count/fill

// ---------------- Layer-1 GEMM + fused attention dots (R7: 8x8 tile) --------
// LDS model: bytes = N*512*64*4*(1/R+1/C) @ ~52 TB/s chip LDS.
//   8x4 (R2): 4.9 GB -> 94us ideal, measured 120, VALUBusy 43% (pred 44%).
//   8x8 (R7): 3.28 GB -> 63us ideal, VALU floor 42us -> pred VALUBusy ~67%.
// 128 thr (2 waves), TM=128, TN=64, BK=16 double-buffered, 782 blocks.
// Per k per lane: 2+2 ds_read_b128 vs 64 FMA. Reads: 8 distinct addrs at
// 32B stride per wave -> worst 2-way bank alias (free, m136).
// Cols cg*8..+7 = head cg exactly -> attention dots fully in-lane.
#define TM 128
#define TN 64
#define BK 16
#define XS_LD 132

__global__ __launch_bounds__(128) void k_gemm1(const float* __restrict__ x,
                                               const float* __restrict__ W1,
                                               const float* __restrict__ att_src,
                                               const float* __restrict__ att_dst,
                                               float* __restrict__ h1,
                                               float* __restrict__ a_src,
                                               float* __restrict__ a_dst) {
    __shared__ float xs[2][BK][XS_LD];
    __shared__ float ws[2][BK][68];
    const int t = threadIdx.x;
    const int row_base = blockIdx.x * TM;
    const int rg = t >> 3;            // 0..15 -> rows rg*8..rg*8+7
    const int cg = t & 7;             // 0..7  -> cols cg*8..cg*8+7 (= head cg)

    // staging: x = 512 float4 (128 rows x 4), 4/thread; W = 256 float4, 2/thread
    float4 xr4[4];
    float4 wr4[2];
    auto load_regs = [&](int k0) {
#pragma unroll
        for (int i = 0; i < 4; i++) {
            const int f  = t + 128 * i;
            const int r  = f >> 2;
            const int kq = (f & 3) << 2;
            const int gr = row_base + r;
            xr4[i] = (gr < N_NODES) ? *(const float4*)(x + (size_t)gr * FIN + k0 + kq)
                                    : make_float4(0.f, 0.f, 0.f, 0.f);
        }
#pragma unroll
        for (int i = 0; i < 2; i++) {
            const int f  = t + 128 * i;
            const int kk = f >> 4;
            const int c4 = (f & 15) << 2;
            wr4[i] = *(const float4*)(W1 + (size_t)(k0 + kk) * TN + c4);
        }
    };
    auto store_lds = [&](int buf) {
#pragma unroll
        for (int i = 0; i < 4; i++) {
            const int f  = t + 128 * i;
            const int r  = f >> 2;
            const int kq = (f & 3) << 2;
            xs[buf][kq + 0][r] = xr4[i].x;
            xs[buf][kq + 1][r] = xr4[i].y;
            xs[buf][kq + 2][r] = xr4[i].z;
            xs[buf][kq + 3][r] = xr4[i].w;
        }
#pragma unroll
        for (int i = 0; i < 2; i++) {
            const int f  = t + 128 * i;
            const int kk = f >> 4;
            const int c4 = (f & 15) << 2;
            *(float4*)&ws[buf][kk][c4] = wr4[i];
        }
    };

    float acc[8][8];
#pragma unroll
    for (int i = 0; i < 8; i++)
#pragma unroll
        for (int j = 0; j < 8; j++) acc[i][j] = 0.f;

    load_regs(0);
    store_lds(0);
    __syncthreads();

    int buf = 0;
    for (int k0 = 0; k0 < FIN; k0 += BK, buf ^= 1) {
        const bool more = (k0 + BK < FIN);
        if (more) load_regs(k0 + BK);
#pragma unroll
        for (int k = 0; k < BK; k++) {
            const float4 xa = *(const float4*)&xs[buf][k][rg * 8];
            const float4 xb = *(const float4*)&xs[buf][k][rg * 8 + 4];
            const float4 wa = *(const float4*)&ws[buf][k][cg * 8];
            const float4 wb = *(const float4*)&ws[buf][k][cg * 8 + 4];
            const float xr[8] = {xa.x, xa.y, xa.z, xa.w, xb.x, xb.y, xb.z, xb.w};
            const float wr[8] = {wa.x, wa.y, wa.z, wa.w, wb.x, wb.y, wb.z, wb.w};
#pragma unroll
            for (int i = 0; i < 8; i++)
#pragma unroll
                for (int j = 0; j < 8; j++)
                    acc[i][j] = fmaf(xr[i], wr[j], acc[i][j]);
        }
        if (more) {
            store_lds(buf ^ 1);
            __syncthreads();
        }
    }

    // epilogue: cols = head cg -> dots fully in-lane, no shuffles
    float asv[8], adv[8];
#pragma unroll
    for (int j = 0; j < 8; j++) {
        asv[j] = att_src[cg * 8 + j];
        adv[j] = att_dst[cg * 8 + j];
    }
#pragma unroll
    for (int i = 0; i < 8; i++) {
        const int gr = row_base + rg * 8 + i;
        if (gr < N_NODES) {
            *(float4*)(h1 + (size_t)gr * HC1 + cg * 8) =
                make_float4(acc[i][0], acc[i][1], acc[i][2], acc[i][3]);
            *(float4*)(h1 + (size_t)gr * HC1 + cg * 8 + 4) =
                make_float4(acc[i][4], acc[i][5], acc[i][6], acc[i][7]);
            float s = 0.f, d = 0.f;
#pragma unroll
            for (int j = 0; j < 8; j++) {
                s = fmaf(acc[i][j], asv[j], s);
                d = fmaf(acc[i][j], adv[j], d);
            }
            a_src[gr * H1H + cg] = s;
            a_dst[gr * H1H + cg] = d;
        }
    }
}

// ---------------- CSR build, bucketed (R2 config) ----------------
__global__ __launch_bounds__(256) void k_bcnt(const int* __restrict__ dst, int E,
                                              int* __restrict__ gcnt) {
    __shared__ int lcnt[NBUK];
    for (int i = threadIdx.x; i < NBUK; i += 256) lcnt[i] = 0;
    __syncthreads();
    const int e0 = blockIdx.x * EPB;
#pragma unroll
    for (int i = 0; i < EPB / 256; i++) {
        const int e = e0 + i * 256 + threadIdx.x;
        if (e < E) atomicAdd(&lcnt[dst[e] >> 8], 1);
    }
    __syncthreads();
    for (int i = threadIdx.x; i < NBUK; i += 256)
        if (lcnt[i]) atomicAdd(&gcnt[i], lcnt[i]);
}

__global__ __launch_bounds__(512) void k_bscan(const int* __restrict__ gcnt,
                                               int* __restrict__ gbase,
                                               int* __restrict__ gcur, int E) {
    __shared__ int sm[512];
    const int t = threadIdx.x;
    const int v = (t < NBUK) ? gcnt[t] : 0;
    sm[t] = v;
    __syncthreads();
    for (int off = 1; off < 512; off <<= 1) {
        const int u = (t >= off) ? sm[t - off] : 0;
        __syncthreads();
        sm[t] += u;
        __syncthreads();
    }
    if (t < NBUK) {
        const int b = sm[t] - v;
        gbase[t] = b;
        gcur[t]  = b;
    }
    if (t == 0) gbase[NBUK] = E;
}

__global__ __launch_bounds__(256) void k_bfill(const int* __restrict__ src,
                                               const int* __restrict__ dst, int E,
                                               int* __restrict__ gcur,
                                               int2* __restrict__ pairs) {
    __shared__ int lcnt[NBUK];
    __shared__ int lbase[NBUK];
    for (int i = threadIdx.x; i < NBUK; i += 256) lcnt[i] = 0;
    __syncthreads();
    const int e0 = blockIdx.x * EPB;
#pragma unroll
    for (int i = 0; i < EPB / 256; i++) {
        const int e = e0 + i * 256 + threadIdx.x;
        if (e < E) atomicAdd(&lcnt[dst[e] >> 8], 1);
    }
    __syncthreads();
    for (int i = threadIdx.x; i < NBUK; i += 256)
        lbase[i] = lcnt[i] ? atomicAdd(&gcur[i], lcnt[i]) : 0;
    __syncthreads();
#pragma unroll
    for (int i = 0; i < EPB / 256; i++) {
        const int e = e0 + i * 256 + threadIdx.x;
        if (e < E) {
            const int d = dst[e];
            const int pos = atomicAdd(&lbase[d >> 8], 1);
            pairs[pos] = make_int2(src[e], d);
        }
    }
}

__global__ __launch_bounds__(256) void k_bscatter(const int2* __restrict__ pairs,
                                                  const int* __restrict__ gbase,
                                                  int* __restrict__ offs,
                                                  int* __restrict__ srcsort, int E) {
    __shared__ int ldeg[NPB];
    __shared__ int ltmp[NPB];
    __shared__ int lcur[NPB];
    const int b = blockIdx.x;
    const int tx = threadIdx.x;
    const int node0 = b << 8;
    const int pbeg = gbase[b];
    const int cnt  = gbase[b + 1] - pbeg;

    ldeg[tx] = 0;
    __syncthreads();
    for (int i = tx; i < cnt; i += 256)
        atomicAdd(&ldeg[pairs[pbeg + i].y - node0], 1);
    __syncthreads();
    const int v = ldeg[tx];
    ltmp[tx] = v;
    __syncthreads();
    for (int off = 1; off < 256; off <<= 1) {
        const int u = (tx >= off) ? ltmp[tx - off] : 0;
        __syncthreads();
        ltmp[tx] += u;
        __syncthreads();
    }
    const int mypos = pbeg + ltmp[tx] - v;
    if (node0 + tx < N_NODES) offs[node0 + tx] = mypos;
    lcur[tx] = mypos;
    if (b == NBUK - 1 && tx == 0) offs[N_NODES] = E;
    __syncthreads();
    for (int i = tx; i < cnt; i += 256) {
        const int2 p = pairs[pbeg + i];
        const int pos = atomicAdd(&lcur[p.y - node0], 1);
        srcsort[pos] = p.x;
    }
}

// ---------------- Layer-1: single-pass batched online softmax + aggregate ----------------
__global__ __launch_bounds__(256) void k_agg1(const float* __restrict__ h1,
                                              const float* __restrict__ a_src,
                                              const float* __restrict__ a_dst,
                                              const int* __restrict__ offs,
                                              const int* __restrict__ srcsort,
                                              const float* __restrict__ b1,
                                              float* __restrict__ h1e) {
    const int n = blockIdx.x * 4 + (threadIdx.x >> 6);
    if (n >= N_NODES) return;
    const int lane = threadIdx.x & 63;
    const int hh   = lane >> 3;
    const float adn = a_dst[n * H1H + hh];
    const int beg = offs[n], end = offs[n + 1];

    float e0 = a_src[n * H1H + hh] + adn;
    e0 = e0 > 0.f ? e0 : NEG_SLOPE * e0;
    float m = e0;
    float denom = 1.f;
    float acc = h1[(size_t)n * HC1 + lane];

    int j = beg;
    for (; j + 8 <= end; j += 8) {
        int s[8];
#pragma unroll
        for (int t = 0; t < 8; t++) s[t] = srcsort[j + t];
        float q[8], g[8];
#pragma unroll
        for (int t = 0; t < 8; t++) q[t] = a_src[s[t] * H1H + hh];
#pragma unroll
        for (int t = 0; t < 8; t++) g[t] = h1[(size_t)s[t] * HC1 + lane];
        float f[8];
#pragma unroll
        for (int t = 0; t < 8; t++) {
            const float e = q[t] + adn;
            f[t] = e > 0.f ? e : NEG_SLOPE * e;
        }
        const float cm = fmaxf(fmaxf(fmaxf(f[0], f[1]), fmaxf(f[2], f[3])),
                               fmaxf(fmaxf(f[4], f[5]), fmaxf(f[6], f[7])));
        const float nm = fmaxf(m, cm);
        const float sc = __expf(m - nm);
        float w[8];
#pragma unroll
        for (int t = 0; t < 8; t++) w[t] = __expf(f[t] - nm);
        const float wsum = ((w[0] + w[1]) + (w[2] + w[3])) + ((w[4] + w[5]) + (w[6] + w[7]));
        const float wg = fmaf(w[0], g[0], fmaf(w[1], g[1], fmaf(w[2], g[2], fmaf(w[3], g[3],
                         fmaf(w[4], g[4], fmaf(w[5], g[5], fmaf(w[6], g[6], w[7] * g[7])))))));
        denom = fmaf(denom, sc, wsum);
        acc = fmaf(acc, sc, wg);
        m = nm;
    }
    for (; j + 4 <= end; j += 4) {
        const int s0 = srcsort[j], s1 = srcsort[j + 1];
        const int s2 = srcsort[j + 2], s3 = srcsort[j + 3];
        const float q0 = a_src[s0 * H1H + hh], q1 = a_src[s1 * H1H + hh];
        const float q2 = a_src[s2 * H1H + hh], q3 = a_src[s3 * H1H + hh];
        const float g0 = h1[(size_t)s0 * HC1 + lane];
        const float g1 = h1[(size_t)s1 * HC1 + lane];
        const float g2 = h1[(size_t)s2 * HC1 + lane];
        const float g3 = h1[(size_t)s3 * HC1 + lane];
        float f0 = q0 + adn; f0 = f0 > 0.f ? f0 : NEG_SLOPE * f0;
        float f1 = q1 + adn; f1 = f1 > 0.f ? f1 : NEG_SLOPE * f1;
        float f2 = q2 + adn; f2 = f2 > 0.f ? f2 : NEG_SLOPE * f2;
        float f3 = q3 + adn; f3 = f3 > 0.f ? f3 : NEG_SLOPE * f3;
        const float nm = fmaxf(m, fmaxf(fmaxf(f0, f1), fmaxf(f2, f3)));
        const float sc = __expf(m - nm);
        const float w0 = __expf(f0 - nm), w1 = __expf(f1 - nm);
        const float w2 = __expf(f2 - nm), w3 = __expf(f3 - nm);
        denom = fmaf(denom, sc, (w0 + w1) + (w2 + w3));
        acc = fmaf(acc, sc, fmaf(w0, g0, fmaf(w1, g1, fmaf(w2, g2, w3 * g3))));
        m = nm;
    }
    for (; j < end; j++) {
        const int s = srcsort[j];
        float e = a_src[s * H1H + hh] + adn;
        e = e > 0.f ? e : NEG_SLOPE * e;
        const float g = h1[(size_t)s * HC1 + lane];
        const float nm = fmaxf(m, e);
        const float sc = __expf(m - nm);
        const float w = __expf(e - nm);
        denom = fmaf(denom, sc, w);
        acc = fmaf(acc, sc, w * g);
        m = nm;
    }
    float v = acc / denom + b1[lane];
    h1e[(size_t)n * HC1 + lane] = v > 0.f ? v : (__expf(v) - 1.f);
}

// ---------------- Layer-2 GEMM (64->40), LDS-tiled, + fused attention dots ----
#define TM2 128
__global__ __launch_bounds__(256) void k_gemm2(const float* __restrict__ h1e,
                                               const float* __restrict__ W2,
                                               const float* __restrict__ att_src2,
                                               const float* __restrict__ att_dst2,
                                               float* __restrict__ h2,
                                               float* __restrict__ a_src2,
                                               float* __restrict__ a_dst2) {
    __shared__ float hs[32][65][4];   // [node_group][k(+pad)][node_in_group]
    __shared__ float w2t[NCLS][68];   // transposed W2, padded
    __shared__ float asv[NCLS], adv[NCLS];
    const int tx = threadIdx.x;
    const int node0 = blockIdx.x * TM2;

    for (int f = tx; f < HC1 * NCLS; f += 256) {
        const int k = f / NCLS, c = f - k * NCLS;
        w2t[c][k] = W2[f];
    }
    if (tx < NCLS) {
        asv[tx] = att_src2[tx];
        adv[tx] = att_dst2[tx];
    }
#pragma unroll
    for (int i = 0; i < 8; i++) {
        const int f  = tx + 256 * i;      // 2048 float4 = 128 rows x 16
        const int n  = f >> 4;
        const int k4 = (f & 15) << 2;
        const int gn = node0 + n;
        const float4 v = (gn < N_NODES) ? *(const float4*)(h1e + (size_t)gn * HC1 + k4)
                                        : make_float4(0.f, 0.f, 0.f, 0.f);
        const int ng = n >> 2, ni = n & 3;
        hs[ng][k4 + 0][ni] = v.x;
        hs[ng][k4 + 1][ni] = v.y;
        hs[ng][k4 + 2][ni] = v.z;
        hs[ng][k4 + 3][ni] = v.w;
    }
    __syncthreads();

    const int ng = tx >> 3;          // 0..31 -> nodes ng*4..ng*4+3
    const int cg = tx & 7;           // 0..7  -> classes cg*5..cg*5+4
    const int c0 = cg * 5;

    float acc[4][5];
#pragma unroll
    for (int i = 0; i < 4; i++)
#pragma unroll
        for (int j = 0; j < 5; j++) acc[i][j] = 0.f;

    for (int k = 0; k < HC1; k += 4) {
        float4 hv[4];
#pragma unroll
        for (int t = 0; t < 4; t++) hv[t] = *(const float4*)&hs[ng][k + t][0];
#pragma unroll
        for (int j = 0; j < 5; j++) {
            const float4 wv = *(const float4*)&w2t[c0 + j][k];
            acc[0][j] = fmaf(hv[0].x, wv.x, fmaf(hv[1].x, wv.y, fmaf(hv[2].x, wv.z, fmaf(hv[3].x, wv.w, acc[0][j]))));
            acc[1][j] = fmaf(hv[0].y, wv.x, fmaf(hv[1].y, wv.y, fmaf(hv[2].y, wv.z, fmaf(hv[3].y, wv.w, acc[1][j]))));
            acc[2][j] = fmaf(hv[0].z, wv.x, fmaf(hv[1].z, wv.y, fmaf(hv[2].z, wv.z, fmaf(hv[3].z, wv.w, acc[2][j]))));
            acc[3][j] = fmaf(hv[0].w, wv.x, fmaf(hv[1].w, wv.y, fmaf(hv[2].w, wv.z, fmaf(hv[3].w, wv.w, acc[3][j]))));
        }
    }

    // store h2 + fused att dots (reduce partials over the 8 cg lanes)
    float ps[4], pd[4];
#pragma unroll
    for (int i = 0; i < 4; i++) {
        const int gn = node0 + ng * 4 + i;
        float s = 0.f, d = 0.f;
#pragma unroll
        for (int j = 0; j < 5; j++) {
            s = fmaf(acc[i][j], asv[c0 + j], s);
            d = fmaf(acc[i][j], adv[c0 + j], d);
        }
        ps[i] = s;
        pd[i] = d;
        if (gn < N_NODES) {
#pragma unroll
            for (int j = 0; j < 5; j++)
                h2[(size_t)gn * NCLS + c0 + j] = acc[i][j];
        }
    }
#pragma unroll
    for (int off = 1; off < 8; off <<= 1) {
#pragma unroll
        for (int i = 0; i < 4; i++) {
            ps[i] += __shfl_xor(ps[i], off, 64);
            pd[i] += __shfl_xor(pd[i], off, 64);
        }
    }
    if (cg == 0) {
#pragma unroll
        for (int i = 0; i < 4; i++) {
            const int gn = node0 + ng * 4 + i;
            if (gn < N_NODES) {
                a_src2[gn] = ps[i];
                a_dst2[gn] = pd[i];
            }
        }
    }
}

// ---------------- Layer-2: single-pass online softmax-aggregate + class softmax ----------------
__global__ __launch_bounds__(256) void k_agg2(const float* __restrict__ h2,
                                              const float* __restrict__ a_src,
                                              const float* __restrict__ a_dst,
                                              const int* __restrict__ offs,
                                              const int* __restrict__ srcsort,
                                              const float* __restrict__ b2,
                                              float* __restrict__ out) {
    const int n = blockIdx.x * 4 + (threadIdx.x >> 6);
    if (n >= N_NODES) return;
    const int lane = threadIdx.x & 63;
    const float adn = a_dst[n];
    const int beg = offs[n], end = offs[n + 1];

    float e0 = a_src[n] + adn;
    e0 = e0 > 0.f ? e0 : NEG_SLOPE * e0;
    float m = e0;
    float denom = 1.f;
    float acc = (lane < NCLS) ? h2[(size_t)n * NCLS + lane] : 0.f;

    int j = beg;
    for (; j + 8 <= end; j += 8) {
        int s[8];
#pragma unroll
        for (int t = 0; t < 8; t++) s[t] = srcsort[j + t];
        float q[8], g[8];
#pragma unroll
        for (int t = 0; t < 8; t++) q[t] = a_src[s[t]];
#pragma unroll
        for (int t = 0; t < 8; t++)
            g[t] = (lane < NCLS) ? h2[(size_t)s[t] * NCLS + lane] : 0.f;
        float f[8];
#pragma unroll
        for (int t = 0; t < 8; t++) {
            const float e = q[t] + adn;
            f[t] = e > 0.f ? e : NEG_SLOPE * e;
        }
        const float cm = fmaxf(fmaxf(fmaxf(f[0], f[1]), fmaxf(f[2], f[3])),
                               fmaxf(fmaxf(f[4], f[5]), fmaxf(f[6], f[7])));
        const float nm = fmaxf(m, cm);
        const float sc = __expf(m - nm);
        float w[8];
#pragma unroll
        for (int t = 0; t < 8; t++) w[t] = __expf(f[t] - nm);
        const float wsum = ((w[0] + w[1]) + (w[2] + w[3])) + ((w[4] + w[5]) + (w[6] + w[7]));
        const float wg = fmaf(w[0], g[0], fmaf(w[1], g[1], fmaf(w[2], g[2], fmaf(w[3], g[3],
                         fmaf(w[4], g[4], fmaf(w[5], g[5], fmaf(w[6], g[6], w[7] * g[7])))))));
        denom = fmaf(denom, sc, wsum);
        acc = fmaf(acc, sc, wg);
        m = nm;
    }
    for (; j + 4 <= end; j += 4) {
        const int s0 = srcsort[j], s1 = srcsort[j + 1];
        const int s2 = srcsort[j + 2], s3 = srcsort[j + 3];
        const float q0 = a_src[s0], q1 = a_src[s1];
        const float q2 = a_src[s2], q3 = a_src[s3];
        float g0 = 0.f, g1 = 0.f, g2 = 0.f, g3 = 0.f;
        if (lane < NCLS) {
            g0 = h2[(size_t)s0 * NCLS + lane];
            g1 = h2[(size_t)s1 * NCLS + lane];
            g2 = h2[(size_t)s2 * NCLS + lane];
            g3 = h2[(size_t)s3 * NCLS + lane];
        }
        float f0 = q0 + adn; f0 = f0 > 0.f ? f0 : NEG_SLOPE * f0;
        float f1 = q1 + adn; f1 = f1 > 0.f ? f1 : NEG_SLOPE * f1;
        float f2 = q2 + adn; f2 = f2 > 0.f ? f2 : NEG_SLOPE * f2;
        float f3 = q3 + adn; f3 = f3 > 0.f ? f3 : NEG_SLOPE * f3;
        const float nm = fmaxf(m, fmaxf(fmaxf(f0, f1), fmaxf(f2, f3)));
        const float sc = __expf(m - nm);
        const float w0 = __expf(f0 - nm), w1 = __expf(f1 - nm);
        const float w2 = __expf(f2 - nm), w3 = __expf(f3 - nm);
        denom = fmaf(denom, sc, (w0 + w1) + (w2 + w3));
        acc = fmaf(acc, sc, fmaf(w0, g0, fmaf(w1, g1, fmaf(w2, g2, w3 * g3))));
        m = nm;
    }
    for (; j < end; j++) {
        const int s = srcsort[j];
        float e = a_src[s] + adn;
        e = e > 0.f ? e : NEG_SLOPE * e;
        const float g = (lane < NCLS) ? h2[(size_t)s * NCLS + lane] : 0.f;
        const float nm = fmaxf(m, e);
        const float sc = __expf(m - nm);
        const float w = __expf(e - nm);
        denom = fmaf(denom, sc, w);
        acc = fmaf(acc, sc, w * g);
        m = nm;
    }
    float o = (lane < NCLS) ? (acc / denom + b2[lane]) : -INFINITY;
    float mx = o;
#pragma unroll
    for (int off = 32; off; off >>= 1) mx = fmaxf(mx, __shfl_xor(mx, off, 64));
    const float ex = (lane < NCLS) ? __expf(o - mx) : 0.f;
    float sm = ex;
#pragma unroll
    for (int off = 32; off; off >>= 1) sm += __shfl_xor(sm, off, 64);
    if (lane < NCLS) out[(size_t)n * NCLS + lane] = ex / sm;
}

// ---------------- launcher ----------------
extern "C" void kernel_launch(void* const* d_in, const int* in_sizes, int n_in,
                              void* d_out, int out_size, void* d_ws, size_t ws_size,
                              hipStream_t stream) {
    const float* x   = (const float*)d_in[0];
    const int*   ei  = (const int*)d_in[1];
    const float* W1v = (const float*)d_in[2];
    const float* as1 = (const float*)d_in[3];
    const float* ad1 = (const float*)d_in[4];
    const float* b1  = (const float*)d_in[5];
    const float* W2v = (const float*)d_in[6];
    const float* as2 = (const float*)d_in[7];
    const float* ad2 = (const float*)d_in[8];
    const float* b2  = (const float*)d_in[9];
    const int E = in_sizes[1] / 2;
    const int* esrc = ei;
    const int* edst = ei + E;

    char* wp = (char*)d_ws;
    auto alloc = [&](size_t bytes) {
        char* p = wp;
        wp += (bytes + 255) & ~(size_t)255;
        return p;
    };
    float* h1     = (float*)alloc((size_t)N_NODES * HC1 * 4);
    float* h1e    = (float*)alloc((size_t)N_NODES * HC1 * 4);
    float* a_src1 = (float*)alloc((size_t)N_NODES * H1H * 4);
    float* a_dst1 = (float*)alloc((size_t)N_NODES * H1H * 4);
    float* a_src2 = (float*)alloc((size_t)N_NODES * 4);
    float* a_dst2 = (float*)alloc((size_t)N_NODES * 4);
    int*   offs   = (int*)alloc((size_t)(N_NODES + 1) * 4);
    int*   gcnt   = (int*)alloc((size_t)NBUK * 4);
    int*   gbase  = (int*)alloc((size_t)(NBUK + 1) * 4);
    int*   gcur   = (int*)alloc((size_t)NBUK * 4);
    int*   srcsort= (int*)alloc((size_t)E * 4);
    int2*  pairs  = (int2*)alloc((size_t)E * 8);
    float* h2     = h1;  // h1 dead after k_agg1; reuse for h2

    hipMemsetAsync(gcnt, 0, (size_t)NBUK * 4, stream);

    const int NEB = (E + EPB - 1) / EPB;
    k_gemm1<<<(N_NODES + TM - 1) / TM, 128, 0, stream>>>(x, W1v, as1, ad1, h1, a_src1, a_dst1);
    k_bcnt<<<NEB, 256, 0, stream>>>(edst, E, gcnt);
    k_bscan<<<1, 512, 0, stream>>>(gcnt, gbase, gcur, E);
    k_bfill<<<NEB, 256, 0, stream>>>(esrc, edst, E, gcur, pairs);
    k_bscatter<<<NBUK, 256, 0, stream>>>(pairs, gbase, offs, srcsort, E);
    k_agg1<<<(N_NODES + 3) / 4, 256, 0, stream>>>(h1, a_src1, a_dst1, offs, srcsort, b1, h1e);
    k_gemm2<<<(N_NODES + TM2 - 1) / TM2, 256, 0, stream>>>(h1e, W2v, as2, ad2, h2, a_src2, a_dst2);
    k_agg2<<<(N_NODES + 3) / 4, 256, 0, stream>>>(h2, a_src2, a_dst2, offs, srcsort, b2, (float*)d_out);
}